// Round 6
// baseline (459.124 us; speedup 1.0000x reference)
//
#include <hip/hip_runtime.h>
#include <math.h>

#define Nn 4096
#define Ee 32768
#define Bb 64
#define FINc 128
#define Dd 64
#define SIGf 0.15f
#define LAMf 0.01f
#define EPSf 1e-5f
#define KX 4224              // 4096 (hf) + 64 (S-row for b2) + 64 (out-row for rootw)
#define W2L (64*KX)          // per-layer w2extT stride (shorts)

typedef __attribute__((ext_vector_type(8))) short bf16x8;
typedef __attribute__((ext_vector_type(4))) float f32x4;

__device__ inline short f2bf(float f) {
  union { float f; unsigned u; } v; v.f = f;
  unsigned r = v.u + 0x7fffu + ((v.u >> 16) & 1u);
  return (short)(r >> 16);
}
__device__ inline float bf2f(short s) {
  union { unsigned u; float f; } v; v.u = ((unsigned)(unsigned short)s) << 16;
  return v.f;
}
__device__ inline bf16x8 pack8v(f32x4 a, f32x4 b) {
  bf16x8 r;
  r[0]=f2bf(a.x); r[1]=f2bf(a.y); r[2]=f2bf(a.z); r[3]=f2bf(a.w);
  r[4]=f2bf(b.x); r[5]=f2bf(b.y); r[6]=f2bf(b.z); r[7]=f2bf(b.w);
  return r;
}
__device__ inline float sigm(float x) { return 1.f / (1.f + expf(-x)); }

// ================= setup: w2extT transpose + packs + count + pcnt + tkl =================
// blocks 0..191: w2->w2extT | 192..199: small packs | 200..327: count | 328: tkl
__global__ __launch_bounds__(256) void k_setup(
    const float* __restrict__ w1, const float* __restrict__ w2,
    const float* __restrict__ b2, const float* __restrict__ rootw,
    const float* __restrict__ gwih, const float* __restrict__ gwhh,
    const float* __restrict__ preW,
    const float* __restrict__ preb, const float* __restrict__ postW,
    const float* __restrict__ postb, const float* __restrict__ outW,
    const float* __restrict__ outb,
    const int* __restrict__ dst, const int* __restrict__ batch,
    short* __restrict__ w1T, short* __restrict__ w2extT,
    short* __restrict__ gwihB, short* __restrict__ gwhhB,
    short* __restrict__ preWT,
    float* __restrict__ cnt, float* __restrict__ pcnt, float* __restrict__ y) {
  const int b = blockIdx.x, tid = threadIdx.x;
  if (b < 192) {
    __shared__ float tile[64*65];
    const int l = b >> 6, h = b & 63;
    const float* srcp = w2 + (size_t)(l*64 + h)*4096;
    #pragma unroll
    for (int it = 0; it < 16; ++it) {
      int j = tid + 256*it;                 // j = f*64 + o (coalesced read)
      tile[(j >> 6)*65 + (j & 63)] = srcp[j];
    }
    __syncthreads();
    short* dl = w2extT + (size_t)l*W2L;
    #pragma unroll
    for (int it = 0; it < 16; ++it) {
      int j = tid + 256*it;                 // j = o*64 + f
      int o = j >> 6, f = j & 63;
      dl[(size_t)o*KX + h*64 + f] = f2bf(tile[f*65 + o]);
    }
  } else if (b < 200) {
    int base = (b - 192)*256 + tid;         // 0..2047
    for (int idx = base; idx < 12288; idx += 2048) {
      int l = idx >> 12, r = idx & 4095;
      int f = r & 63, c = r >> 6;
      w1T[idx] = f2bf(w1[l*4096 + f*64 + c]);
      // b2 row-block (k = 4096+f), rootw row-block (k = 4160+f)
      w2extT[(size_t)l*W2L + (size_t)c*KX + 4096 + f] = f2bf(b2[l*4096 + f*64 + c]);
      w2extT[(size_t)l*W2L + (size_t)c*KX + 4160 + f] = f2bf(rootw[l*4096 + f*64 + c]);
    }
    for (int idx = base; idx < 36864; idx += 2048) {
      gwihB[idx] = f2bf(gwih[idx]);
      gwhhB[idx] = f2bf(gwhh[idx]);
    }
    for (int idx = base; idx < 8192; idx += 2048) {
      int k = idx & 127, d = idx >> 7;
      preWT[idx] = f2bf(preW[k*64 + d]);
    }
  } else if (b < 328) {
    int e = (b - 200)*256 + tid;
    atomicAdd(&cnt[dst[e]], 1.0f);
    if (e < Nn) atomicAdd(&pcnt[batch[e]], 1.0f);
  } else {
    const float logc = logf(SIGf * sqrtf(6.28318530717958647692f));
    const float c2 = 0.5f / (SIGf * SIGf);
    float acc = 0.f;
    for (int i = tid; i < FINc*Dd; i += 256) { float w = preW[i];  acc += c2*w*w + logc; }
    for (int i = tid; i < Dd; i += 256)      { float w = preb[i];  acc += c2*w*w + logc; }
    for (int i = tid; i < Dd*Dd; i += 256)   { float w = postW[i]; acc += c2*w*w + logc; }
    for (int i = tid; i < Dd; i += 256)      { float w = postb[i]; acc += c2*w*w + logc; }
    for (int i = tid; i < Dd; i += 256)      { float w = outW[i];  acc += c2*w*w + logc; }
    if (tid == 0)                            { float w = outb[0];  acc += c2*w*w + logc; }
    __shared__ float red[256];
    red[tid] = acc; __syncthreads();
    for (int s = 128; s > 0; s >>= 1) { if (tid < s) red[tid] += red[tid+s]; __syncthreads(); }
    if (tid == 0) y[Bb] = red[0];
  }
}

// ---------------- CSR prefix sum over cnt (4096) ----------------
__global__ __launch_bounds__(256) void k_scan(const float* __restrict__ cnt,
                                              int* __restrict__ rowstart,
                                              int* __restrict__ cursor) {
  __shared__ int sh[256];
  const int tid = threadIdx.x;
  int loc[16]; int s = 0;
  #pragma unroll
  for (int i = 0; i < 16; ++i) { loc[i] = s; s += (int)cnt[tid*16 + i]; }
  sh[tid] = s; __syncthreads();
  for (int off = 1; off < 256; off <<= 1) {
    int v = (tid >= off) ? sh[tid - off] : 0;
    __syncthreads();
    sh[tid] += v;
    __syncthreads();
  }
  int base = (tid > 0) ? sh[tid - 1] : 0;
  #pragma unroll
  for (int i = 0; i < 16; ++i) {
    rowstart[tid*16 + i] = base + loc[i];
    cursor[tid*16 + i]   = base + loc[i];
  }
  if (tid == 255) rowstart[4096] = sh[255];
}

// ---------------- CSR scatter: perm (edge ids by dst), srcp (src by dst) ----------------
__global__ void k_scatter(const int* __restrict__ src, const int* __restrict__ dst,
                          int* __restrict__ cursor, int* __restrict__ perm,
                          int* __restrict__ srcp) {
  int e = blockIdx.x * 256 + threadIdx.x;
  int d = dst[e];
  int pos = atomicAdd(&cursor[d], 1);
  perm[pos] = e;
  srcp[pos] = src[e];
}

// ---------------- pre FC + relu via MFMA ----------------
__global__ __launch_bounds__(256) void k_pre(const float* __restrict__ x,
                                             const short* __restrict__ preWT,
                                             const float* __restrict__ preb,
                                             float* __restrict__ out, float* __restrict__ h) {
  const int tid = threadIdx.x, lane = tid & 63, wave = tid >> 6;
  const int m15 = lane & 15, kq = lane >> 4;
  const int nb = blockIdx.x * 32;
  const f32x4 zero4 = {0.f,0.f,0.f,0.f};
  const int d = wave*16 + m15;
  bf16x8 bfr[4];
  #pragma unroll
  for (int c = 0; c < 4; ++c)
    bfr[c] = *(const bf16x8*)(preWT + d*128 + c*32 + kq*8);
  #pragma unroll
  for (int t = 0; t < 2; ++t) {
    const float* xp = x + (size_t)(nb + t*16 + m15)*128 + kq*8;
    f32x4 p = zero4;
    #pragma unroll
    for (int c = 0; c < 4; ++c) {
      bf16x8 a = pack8v(*(const f32x4*)(xp + c*32), *(const f32x4*)(xp + c*32 + 4));
      p = __builtin_amdgcn_mfma_f32_16x16x32_bf16(a, bfr[c], p, 0, 0, 0);
    }
    float bv = preb[d];
    #pragma unroll
    for (int r = 0; r < 4; ++r) {
      int node = nb + t*16 + kq*4 + r;
      float v = fmaxf(p[r] + bv, 0.f);
      out[node*64 + d] = v;
      h[node*64 + d] = v;
    }
  }
}

// ---------------- hid = relu(edge_attr[perm] @ w1 + b1), CSR order, bf16 ----------------
__global__ __launch_bounds__(256) void k_hid(
    const float* __restrict__ ea, const short* __restrict__ w1T,
    const float* __restrict__ b1, const int* __restrict__ perm,
    short* __restrict__ hid_p) {
  __shared__ int eidv[64];
  const int tid = threadIdx.x, lane = tid & 63, wave = tid >> 6;
  const int m15 = lane & 15, kq = lane >> 4;
  const int pbase = blockIdx.x * 64;
  if (tid < 64) eidv[tid] = perm[pbase + tid];
  __syncthreads();
  const f32x4 zero4 = {0.f,0.f,0.f,0.f};
  const short* wp = w1T + (wave*16 + m15)*64 + kq*8;
  bf16x8 bw0 = *(const bf16x8*)(wp);
  bf16x8 bw1 = *(const bf16x8*)(wp + 32);
  float b1v = b1[wave*16 + m15];
  #pragma unroll
  for (int t = 0; t < 4; ++t) {
    const float* ep = ea + (size_t)eidv[t*16 + m15]*64 + kq*8;
    bf16x8 a0 = pack8v(*(const f32x4*)(ep),      *(const f32x4*)(ep + 4));
    bf16x8 a1 = pack8v(*(const f32x4*)(ep + 32), *(const f32x4*)(ep + 36));
    f32x4 p = __builtin_amdgcn_mfma_f32_16x16x32_bf16(a0, bw0, zero4, 0, 0, 0);
    p = __builtin_amdgcn_mfma_f32_16x16x32_bf16(a1, bw1, p, 0, 0, 0);
    #pragma unroll
    for (int r = 0; r < 4; ++r)
      hid_p[(size_t)(pbase + t*16 + kq*4 + r)*64 + wave*16 + m15] =
        f2bf(fmaxf(p[r] + b1v, 0.f));
  }
}

// ---------------- per-node outer-product accumulation: Ghat = [sum hid⊗s | sum s | out]/c ----------------
__global__ __launch_bounds__(256) void k_outer(
    const float* __restrict__ out, const short* __restrict__ hid_p,
    const int* __restrict__ srcp, const int* __restrict__ rowstart,
    short* __restrict__ gbuf) {
  const int tid = threadIdx.x, lane = tid & 63;
  const int node = blockIdx.x * 4 + (tid >> 6);
  const int r0 = rowstart[node], r1 = rowstart[node + 1];
  const float inv = 1.f / fmaxf((float)(r1 - r0), 1.f);
  float G[64];
  #pragma unroll
  for (int r = 0; r < 64; ++r) G[r] = 0.f;
  float S = 0.f;
  for (int p = r0; p < r1; ++p) {
    float sv = out[(size_t)srcp[p]*64 + lane];
    float hv = bf2f(hid_p[(size_t)p*64 + lane]);
    S += sv;
    #pragma unroll
    for (int r = 0; r < 64; ++r) G[r] += __shfl(hv, r, 64) * sv;
  }
  short* gp = gbuf + (size_t)node*KX;
  #pragma unroll
  for (int r = 0; r < 64; ++r) gp[r*64 + lane] = f2bf(G[r] * inv);
  gp[4096 + lane] = f2bf(S * inv);
  gp[4160 + lane] = f2bf(out[(size_t)node*64 + lane]);
}

// ---------------- m = Ghat @ W2ext + rootb ; softmax ; BN stats (fused) ----------------
// 256 blocks x 16 nodes; 4 waves split K (4224 = 4 x 33 x 32); LDS reduce; epilogue.
__global__ __launch_bounds__(256) void k_gemm2m(
    const short* __restrict__ gbuf, const short* __restrict__ w2extT,
    const float* __restrict__ rootb, const float* __restrict__ gnlin,
    float* __restrict__ m, float* __restrict__ sbuf, float* __restrict__ stats) {
  __shared__ __align__(16) float red[3*64*20];
  __shared__ float msh[16*65];
  __shared__ float lgsh[16*12];
  __shared__ float ssh[16*16];
  const int tid = threadIdx.x, lane = tid & 63, wave = tid >> 6;
  const int m15 = lane & 15, kq = lane >> 4;
  const int nb = blockIdx.x * 16;
  const f32x4 zero4 = {0.f,0.f,0.f,0.f};

  f32x4 acc[4] = {zero4, zero4, zero4, zero4};
  const short* ga = gbuf + (size_t)(nb + m15)*KX + wave*1056 + kq*8;
  const short* wb0 = w2extT + (size_t)(0*16 + m15)*KX + wave*1056 + kq*8;
  const short* wb1 = w2extT + (size_t)(1*16 + m15)*KX + wave*1056 + kq*8;
  const short* wb2 = w2extT + (size_t)(2*16 + m15)*KX + wave*1056 + kq*8;
  const short* wb3 = w2extT + (size_t)(3*16 + m15)*KX + wave*1056 + kq*8;
  #pragma unroll 3
  for (int c = 0; c < 33; ++c) {
    bf16x8 a  = *(const bf16x8*)(ga + c*32);
    bf16x8 b0 = *(const bf16x8*)(wb0 + c*32);
    bf16x8 b1 = *(const bf16x8*)(wb1 + c*32);
    bf16x8 b2 = *(const bf16x8*)(wb2 + c*32);
    bf16x8 b3 = *(const bf16x8*)(wb3 + c*32);
    acc[0] = __builtin_amdgcn_mfma_f32_16x16x32_bf16(a, b0, acc[0], 0, 0, 0);
    acc[1] = __builtin_amdgcn_mfma_f32_16x16x32_bf16(a, b1, acc[1], 0, 0, 0);
    acc[2] = __builtin_amdgcn_mfma_f32_16x16x32_bf16(a, b2, acc[2], 0, 0, 0);
    acc[3] = __builtin_amdgcn_mfma_f32_16x16x32_bf16(a, b3, acc[3], 0, 0, 0);
  }
  if (wave) {
    #pragma unroll
    for (int ot = 0; ot < 4; ++ot)
      *(f32x4*)(red + ((wave - 1)*64 + lane)*20 + ot*4) = acc[ot];
  }
  __syncthreads();
  if (!wave) {
    #pragma unroll
    for (int j = 0; j < 3; ++j)
      #pragma unroll
      for (int ot = 0; ot < 4; ++ot) {
        f32x4 v = *(const f32x4*)(red + ((j*64 + lane)*20) + ot*4);
        acc[ot].x += v.x; acc[ot].y += v.y; acc[ot].z += v.z; acc[ot].w += v.w;
      }
    #pragma unroll
    for (int ot = 0; ot < 4; ++ot) {
      int col = ot*16 + m15;
      float rbv = rootb[col];
      #pragma unroll
      for (int r = 0; r < 4; ++r) {
        int row = kq*4 + r;
        float mv = acc[ot][r] + rbv;
        m[(size_t)(nb + row)*64 + col] = mv;
        msh[row*65 + col] = mv;
      }
    }
  }
  __syncthreads();
  // logits: 16 nodes x 10 groups
  if (tid < 160) {
    int n = tid / 10, g = tid - n*10;
    float lg = 0.f;
    #pragma unroll 8
    for (int k = 0; k < 64; ++k) lg += msh[n*65 + k] * gnlin[k*10 + g];
    lgsh[n*12 + g] = lg;
  }
  __syncthreads();
  {
    int n = tid >> 4, g = tid & 15;
    if (g < 10) {
      float mx = -1e30f;
      #pragma unroll
      for (int gg = 0; gg < 10; ++gg) mx = fmaxf(mx, lgsh[n*12 + gg]);
      float sum = 0.f;
      #pragma unroll
      for (int gg = 0; gg < 10; ++gg) sum += expf(lgsh[n*12 + gg] - mx);
      float sv = expf(lgsh[n*12 + g] - mx) / sum;
      sbuf[(nb + n)*16 + g] = sv;
      ssh[n*16 + g] = sv;
    }
  }
  __syncthreads();
  for (int c = tid; c < 640; c += 256) {
    int g = c >> 6, dd = c & 63;
    float a1 = 0.f, a2 = 0.f;
    #pragma unroll
    for (int n = 0; n < 16; ++n) {
      float t = ssh[n*16 + g] * msh[n*65 + dd];
      a1 += t; a2 += t*t;
    }
    atomicAdd(&stats[c], a1);
    atomicAdd(&stats[640 + c], a2);
  }
}

// ---------------- DGN-finalize + relu + GRU (MFMA) + residual (+ pooling on last) ----------------
__global__ __launch_bounds__(256) void k_gru(
    const float* __restrict__ m, const float* __restrict__ sbuf,
    const float* __restrict__ stats, const float* __restrict__ gamma,
    const float* __restrict__ beta, const short* __restrict__ gwihB,
    const short* __restrict__ gwhhB, const float* __restrict__ bih,
    const float* __restrict__ bhh, float* __restrict__ h,
    float* __restrict__ out, const int* __restrict__ batch,
    float* __restrict__ pooled, int do_pool) {
  __shared__ __align__(16) float mrsh[32*68];
  __shared__ float igsh[640];
  __shared__ float Bsh[64];
  __shared__ float ssh[512];
  const int tid = threadIdx.x, lane = tid & 63, wave = tid >> 6;
  const int m15 = lane & 15, kq = lane >> 4;
  const int nb = blockIdx.x * 32;
  const f32x4 zero4 = {0.f,0.f,0.f,0.f};
  const float invN = 1.f / (float)Nn;

  if (tid < 64) {
    float bacc = 0.f;
    #pragma unroll
    for (int g = 0; g < 10; ++g) {
      int c = g*64 + tid;
      float mu = stats[c] * invN;
      float var = stats[640 + c] * invN - mu*mu;
      float ig = (1.0f / sqrtf(var + EPSf)) * gamma[c];
      igsh[c] = ig;
      bacc += beta[c] - mu * ig;
    }
    Bsh[tid] = bacc;
  }
  if (tid < 512) ssh[tid] = sbuf[nb*16 + tid];
  __syncthreads();

  for (int idx = tid; idx < 2048; idx += 256) {
    int n = idx >> 6, dd = idx & 63;
    float mv = m[(nb + n)*64 + dd];
    float SA = 0.f;
    #pragma unroll
    for (int g = 0; g < 10; ++g) SA += ssh[n*16 + g] * igsh[g*64 + dd];
    mrsh[n*68 + dd] = fmaxf(mv * (1.f + LAMf*SA) + LAMf*Bsh[dd], 0.f);
  }
  __syncthreads();

  bf16x8 mrf[2][2], hf[2][2];
  #pragma unroll
  for (int t = 0; t < 2; ++t) {
    const float* mp = mrsh + (t*16 + m15)*68 + kq*8;
    const float* hp = h + (size_t)(nb + t*16 + m15)*64 + kq*8;
    #pragma unroll
    for (int ks = 0; ks < 2; ++ks) {
      mrf[t][ks] = pack8v(*(const f32x4*)(mp + ks*32), *(const f32x4*)(mp + ks*32 + 4));
      hf[t][ks]  = pack8v(*(const f32x4*)(hp + ks*32), *(const f32x4*)(hp + ks*32 + 4));
    }
  }
  const int d = wave*16 + m15;
  f32x4 gi[2][3], gh[2][3];
  #pragma unroll
  for (int p = 0; p < 3; ++p) {
    int j = p*64 + d;
    bf16x8 bi0 = *(const bf16x8*)(gwihB + j*64 + kq*8);
    bf16x8 bi1 = *(const bf16x8*)(gwihB + j*64 + 32 + kq*8);
    bf16x8 bh0 = *(const bf16x8*)(gwhhB + j*64 + kq*8);
    bf16x8 bh1 = *(const bf16x8*)(gwhhB + j*64 + 32 + kq*8);
    #pragma unroll
    for (int t = 0; t < 2; ++t) {
      f32x4 a = __builtin_amdgcn_mfma_f32_16x16x32_bf16(mrf[t][0], bi0, zero4, 0, 0, 0);
      gi[t][p] = __builtin_amdgcn_mfma_f32_16x16x32_bf16(mrf[t][1], bi1, a, 0, 0, 0);
      f32x4 b = __builtin_amdgcn_mfma_f32_16x16x32_bf16(hf[t][0], bh0, zero4, 0, 0, 0);
      gh[t][p] = __builtin_amdgcn_mfma_f32_16x16x32_bf16(hf[t][1], bh1, b, 0, 0, 0);
    }
  }
  float bir = bih[d],      bhr = bhh[d];
  float biz = bih[64 + d], bhz = bhh[64 + d];
  float bin = bih[128 + d], bhn = bhh[128 + d];
  __syncthreads();
  #pragma unroll
  for (int t = 0; t < 2; ++t) {
    #pragma unroll
    for (int r = 0; r < 4; ++r) {
      int node = nb + t*16 + kq*4 + r;
      float rr = sigm(gi[t][0][r] + bir + gh[t][0][r] + bhr);
      float z  = sigm(gi[t][1][r] + biz + gh[t][1][r] + bhz);
      float nn = tanhf(gi[t][2][r] + bin + rr * (gh[t][2][r] + bhn));
      float hv = h[node*64 + d];
      float hn = (1.f - z) * nn + z * hv;
      h[node*64 + d] = hn;
      float ov = hn + out[node*64 + d];
      out[node*64 + d] = ov;
      if (do_pool) atomicAdd(&pooled[batch[node]*64 + d], ov);
    }
  }
}

// ---------------- post FC + output ----------------
__global__ void k_final(const float* __restrict__ pooled, const float* __restrict__ pcnt,
                        const float* __restrict__ postW, const float* __restrict__ postb,
                        const float* __restrict__ outW, const float* __restrict__ outb,
                        float* __restrict__ y) {
  int b = blockIdx.x, d = threadIdx.x;
  __shared__ float pl[64];
  float c = fmaxf(pcnt[b], 1.f);
  pl[d] = pooled[b*64 + d] / c;
  __syncthreads();
  float acc = postb[d];
  #pragma unroll 8
  for (int k = 0; k < 64; ++k) acc += pl[k] * postW[k*64 + d];
  acc = fmaxf(acc, 0.f);
  float v = acc * outW[d];
  #pragma unroll
  for (int off = 32; off > 0; off >>= 1) v += __shfl_down(v, off, 64);
  if (d == 0) y[b] = v + outb[0];
}

extern "C" void kernel_launch(void* const* d_in, const int* in_sizes, int n_in,
                              void* d_out, int out_size, void* d_ws, size_t ws_size,
                              hipStream_t stream) {
  (void)in_sizes; (void)n_in; (void)out_size; (void)ws_size;
  const float* x        = (const float*)d_in[0];
  const float* edge_attr= (const float*)d_in[1];
  const float* preW     = (const float*)d_in[2];
  const float* preb     = (const float*)d_in[3];
  const float* ew1      = (const float*)d_in[4];
  const float* eb1      = (const float*)d_in[5];
  const float* ew2      = (const float*)d_in[6];
  const float* eb2      = (const float*)d_in[7];
  const float* rootw    = (const float*)d_in[8];
  const float* rootb    = (const float*)d_in[9];
  const float* gwih     = (const float*)d_in[10];
  const float* gwhh     = (const float*)d_in[11];
  const float* gbih     = (const float*)d_in[12];
  const float* gbhh     = (const float*)d_in[13];
  const float* gnlin    = (const float*)d_in[14];
  const float* gngamma  = (const float*)d_in[15];
  const float* gnbeta   = (const float*)d_in[16];
  const float* postW    = (const float*)d_in[17];
  const float* postb    = (const float*)d_in[18];
  const float* outW     = (const float*)d_in[19];
  const float* outb     = (const float*)d_in[20];
  const int*   eidx     = (const int*)d_in[21];
  const int*   batch    = (const int*)d_in[22];
  const int* src = eidx;
  const int* dst = eidx + Ee;
  float* y = (float*)d_out;

  float* ws     = (float*)d_ws;
  float* out    = ws;                     // N*64
  float* hbuf   = out    + Nn*64;         // N*64
  float* mbuf   = hbuf   + Nn*64;         // N*64
  float* sbuf   = mbuf   + Nn*64;         // N*16
  // zeroed region: cnt, stats x3, pooled, pcnt
  float* cnt    = sbuf   + Nn*16;         // N
  float* stats  = cnt    + Nn;            // 3*2048
  float* pooled = stats  + 3*2048;        // 4096
  float* pcnt   = pooled + 4096;          // 64
  int* ibase    = (int*)(pcnt + 64);
  int* rowstart = ibase;                  // 4097
  int* cursor   = rowstart + 4097;        // 4096
  int* perm     = cursor + 4096;          // E
  int* srcp     = perm + Ee;              // E
  // pad to 16B boundary (73729 ints -> 73732)
  short* sbase  = (short*)(ibase + 4097 + 4096 + Ee + Ee + 3);
  short* hid_p  = sbase;                  // E*64
  short* gbuf   = hid_p + (size_t)Ee*64;  // N*KX
  short* w2extT = gbuf + (size_t)Nn*KX;   // 3*64*KX
  short* w1T    = w2extT + 3*W2L;         // 3*4096
  short* gwihB  = w1T + 3*4096;           // 3*12288
  short* gwhhB  = gwihB + 3*12288;        // 3*12288
  short* preWT  = gwhhB + 3*12288;        // 8192

  size_t zfloats = (size_t)Nn + 3*2048 + 4096 + 64;
  hipMemsetAsync(cnt, 0, zfloats*sizeof(float), stream);

  k_setup<<<329, 256, 0, stream>>>(ew1, ew2, eb2, rootw, gwih, gwhh, preW,
                                   preb, postW, postb, outW, outb,
                                   dst, batch,
                                   w1T, w2extT, gwihB, gwhhB, preWT,
                                   cnt, pcnt, y);
  k_scan<<<1, 256, 0, stream>>>(cnt, rowstart, cursor);
  k_scatter<<<Ee/256, 256, 0, stream>>>(src, dst, cursor, perm, srcp);
  k_pre<<<Nn/32, 256, 0, stream>>>(x, preWT, preb, out, hbuf);

  for (int i = 0; i < 3; ++i) {
    k_hid<<<Ee/64, 256, 0, stream>>>(edge_attr, w1T + i*4096, eb1 + i*64, perm, hid_p);
    k_outer<<<Nn/4, 256, 0, stream>>>(out, hid_p, srcp, rowstart, gbuf);
    k_gemm2m<<<Nn/16, 256, 0, stream>>>(gbuf, w2extT + (size_t)i*W2L,
                                        rootb + i*64, gnlin + i*640,
                                        mbuf, sbuf, stats + i*2048);
    k_gru<<<Nn/32, 256, 0, stream>>>(mbuf, sbuf, stats + i*2048,
                                     gngamma + i*640, gnbeta + i*640,
                                     gwihB + i*12288, gwhhB + i*12288,
                                     gbih + i*192, gbhh + i*192, hbuf, out,
                                     batch, pooled, (i == 2) ? 1 : 0);
  }

  k_final<<<Bb, 64, 0, stream>>>(pooled, pcnt, postW, postb, outW, outb, y);
}

// Round 7
// 419.095 us; speedup vs baseline: 1.0955x; 1.0955x over previous
//
#include <hip/hip_runtime.h>
#include <math.h>

#define Nn 4096
#define Ee 32768
#define Bb 64
#define FINc 128
#define Dd 64
#define SIGf 0.15f
#define LAMf 0.01f
#define EPSf 1e-5f
#define KX 4224              // 4096 (hf) + 64 (S-row for b2) + 64 (out-row for rootw)
#define W2L (64*KX)          // per-layer w2extT stride (shorts)

typedef __attribute__((ext_vector_type(8))) short bf16x8;
typedef __attribute__((ext_vector_type(4))) float f32x4;

__device__ inline short f2bf(float f) {
  union { float f; unsigned u; } v; v.f = f;
  unsigned r = v.u + 0x7fffu + ((v.u >> 16) & 1u);
  return (short)(r >> 16);
}
__device__ inline float bf2f(short s) {
  union { unsigned u; float f; } v; v.u = ((unsigned)(unsigned short)s) << 16;
  return v.f;
}
__device__ inline bf16x8 pack8v(f32x4 a, f32x4 b) {
  bf16x8 r;
  r[0]=f2bf(a.x); r[1]=f2bf(a.y); r[2]=f2bf(a.z); r[3]=f2bf(a.w);
  r[4]=f2bf(b.x); r[5]=f2bf(b.y); r[6]=f2bf(b.z); r[7]=f2bf(b.w);
  return r;
}
__device__ inline float sigm(float x) { return 1.f / (1.f + expf(-x)); }

// ================= setup: w2extT transpose + packs + count + pcnt + tkl =================
__global__ __launch_bounds__(256) void k_setup(
    const float* __restrict__ w1, const float* __restrict__ w2,
    const float* __restrict__ b2, const float* __restrict__ rootw,
    const float* __restrict__ gwih, const float* __restrict__ gwhh,
    const float* __restrict__ preW,
    const float* __restrict__ preb, const float* __restrict__ postW,
    const float* __restrict__ postb, const float* __restrict__ outW,
    const float* __restrict__ outb,
    const int* __restrict__ dst, const int* __restrict__ batch,
    short* __restrict__ w1T, short* __restrict__ w2extT,
    short* __restrict__ gwihB, short* __restrict__ gwhhB,
    short* __restrict__ preWT,
    float* __restrict__ cnt, float* __restrict__ pcnt, float* __restrict__ y) {
  const int b = blockIdx.x, tid = threadIdx.x;
  if (b < 192) {
    __shared__ float tile[64*65];
    const int l = b >> 6, h = b & 63;
    const float* srcp = w2 + (size_t)(l*64 + h)*4096;
    #pragma unroll
    for (int it = 0; it < 16; ++it) {
      int j = tid + 256*it;                 // j = f*64 + o (coalesced read)
      tile[(j >> 6)*65 + (j & 63)] = srcp[j];
    }
    __syncthreads();
    short* dl = w2extT + (size_t)l*W2L;
    #pragma unroll
    for (int it = 0; it < 16; ++it) {
      int j = tid + 256*it;                 // j = o*64 + f
      int o = j >> 6, f = j & 63;
      dl[(size_t)o*KX + h*64 + f] = f2bf(tile[f*65 + o]);
    }
  } else if (b < 200) {
    int base = (b - 192)*256 + tid;         // 0..2047
    for (int idx = base; idx < 12288; idx += 2048) {
      int l = idx >> 12, r = idx & 4095;
      int f = r & 63, c = r >> 6;
      w1T[idx] = f2bf(w1[l*4096 + f*64 + c]);
      // b2 row-block (k = 4096+f), rootw row-block (k = 4160+f)
      w2extT[(size_t)l*W2L + (size_t)c*KX + 4096 + f] = f2bf(b2[l*4096 + f*64 + c]);
      w2extT[(size_t)l*W2L + (size_t)c*KX + 4160 + f] = f2bf(rootw[l*4096 + f*64 + c]);
    }
    for (int idx = base; idx < 36864; idx += 2048) {
      gwihB[idx] = f2bf(gwih[idx]);
      gwhhB[idx] = f2bf(gwhh[idx]);
    }
    for (int idx = base; idx < 8192; idx += 2048) {
      int k = idx & 127, d = idx >> 7;
      preWT[idx] = f2bf(preW[k*64 + d]);
    }
  } else if (b < 328) {
    int e = (b - 200)*256 + tid;
    atomicAdd(&cnt[dst[e]], 1.0f);
    if (e < Nn) atomicAdd(&pcnt[batch[e]], 1.0f);
  } else {
    const float logc = logf(SIGf * sqrtf(6.28318530717958647692f));
    const float c2 = 0.5f / (SIGf * SIGf);
    float acc = 0.f;
    for (int i = tid; i < FINc*Dd; i += 256) { float w = preW[i];  acc += c2*w*w + logc; }
    for (int i = tid; i < Dd; i += 256)      { float w = preb[i];  acc += c2*w*w + logc; }
    for (int i = tid; i < Dd*Dd; i += 256)   { float w = postW[i]; acc += c2*w*w + logc; }
    for (int i = tid; i < Dd; i += 256)      { float w = postb[i]; acc += c2*w*w + logc; }
    for (int i = tid; i < Dd; i += 256)      { float w = outW[i];  acc += c2*w*w + logc; }
    if (tid == 0)                            { float w = outb[0];  acc += c2*w*w + logc; }
    __shared__ float red[256];
    red[tid] = acc; __syncthreads();
    for (int s = 128; s > 0; s >>= 1) { if (tid < s) red[tid] += red[tid+s]; __syncthreads(); }
    if (tid == 0) y[Bb] = red[0];
  }
}

// ---------------- CSR prefix sum over cnt (4096) ----------------
__global__ __launch_bounds__(256) void k_scan(const float* __restrict__ cnt,
                                              int* __restrict__ rowstart,
                                              int* __restrict__ cursor) {
  __shared__ int sh[256];
  const int tid = threadIdx.x;
  int loc[16]; int s = 0;
  #pragma unroll
  for (int i = 0; i < 16; ++i) { loc[i] = s; s += (int)cnt[tid*16 + i]; }
  sh[tid] = s; __syncthreads();
  for (int off = 1; off < 256; off <<= 1) {
    int v = (tid >= off) ? sh[tid - off] : 0;
    __syncthreads();
    sh[tid] += v;
    __syncthreads();
  }
  int base = (tid > 0) ? sh[tid - 1] : 0;
  #pragma unroll
  for (int i = 0; i < 16; ++i) {
    rowstart[tid*16 + i] = base + loc[i];
    cursor[tid*16 + i]   = base + loc[i];
  }
  if (tid == 255) rowstart[4096] = sh[255];
}

// ---------------- CSR scatter ----------------
__global__ void k_scatter(const int* __restrict__ src, const int* __restrict__ dst,
                          int* __restrict__ cursor, int* __restrict__ perm,
                          int* __restrict__ srcp) {
  int e = blockIdx.x * 256 + threadIdx.x;
  int d = dst[e];
  int pos = atomicAdd(&cursor[d], 1);
  perm[pos] = e;
  srcp[pos] = src[e];
}

// ---------------- pre FC + relu via MFMA ----------------
__global__ __launch_bounds__(256) void k_pre(const float* __restrict__ x,
                                             const short* __restrict__ preWT,
                                             const float* __restrict__ preb,
                                             float* __restrict__ out, float* __restrict__ h) {
  const int tid = threadIdx.x, lane = tid & 63, wave = tid >> 6;
  const int m15 = lane & 15, kq = lane >> 4;
  const int nb = blockIdx.x * 32;
  const f32x4 zero4 = {0.f,0.f,0.f,0.f};
  const int d = wave*16 + m15;
  bf16x8 bfr[4];
  #pragma unroll
  for (int c = 0; c < 4; ++c)
    bfr[c] = *(const bf16x8*)(preWT + d*128 + c*32 + kq*8);
  #pragma unroll
  for (int t = 0; t < 2; ++t) {
    const float* xp = x + (size_t)(nb + t*16 + m15)*128 + kq*8;
    f32x4 p = zero4;
    #pragma unroll
    for (int c = 0; c < 4; ++c) {
      bf16x8 a = pack8v(*(const f32x4*)(xp + c*32), *(const f32x4*)(xp + c*32 + 4));
      p = __builtin_amdgcn_mfma_f32_16x16x32_bf16(a, bfr[c], p, 0, 0, 0);
    }
    float bv = preb[d];
    #pragma unroll
    for (int r = 0; r < 4; ++r) {
      int node = nb + t*16 + kq*4 + r;
      float v = fmaxf(p[r] + bv, 0.f);
      out[node*64 + d] = v;
      h[node*64 + d] = v;
    }
  }
}

// ---------------- hid = relu(edge_attr[perm] @ w1 + b1), CSR order, bf16 ----------------
__global__ __launch_bounds__(256) void k_hid(
    const float* __restrict__ ea, const short* __restrict__ w1T,
    const float* __restrict__ b1, const int* __restrict__ perm,
    short* __restrict__ hid_p) {
  __shared__ int eidv[64];
  const int tid = threadIdx.x, lane = tid & 63, wave = tid >> 6;
  const int m15 = lane & 15, kq = lane >> 4;
  const int pbase = blockIdx.x * 64;
  if (tid < 64) eidv[tid] = perm[pbase + tid];
  __syncthreads();
  const f32x4 zero4 = {0.f,0.f,0.f,0.f};
  const short* wp = w1T + (wave*16 + m15)*64 + kq*8;
  bf16x8 bw0 = *(const bf16x8*)(wp);
  bf16x8 bw1 = *(const bf16x8*)(wp + 32);
  float b1v = b1[wave*16 + m15];
  #pragma unroll
  for (int t = 0; t < 4; ++t) {
    const float* ep = ea + (size_t)eidv[t*16 + m15]*64 + kq*8;
    bf16x8 a0 = pack8v(*(const f32x4*)(ep),      *(const f32x4*)(ep + 4));
    bf16x8 a1 = pack8v(*(const f32x4*)(ep + 32), *(const f32x4*)(ep + 36));
    f32x4 p = __builtin_amdgcn_mfma_f32_16x16x32_bf16(a0, bw0, zero4, 0, 0, 0);
    p = __builtin_amdgcn_mfma_f32_16x16x32_bf16(a1, bw1, p, 0, 0, 0);
    #pragma unroll
    for (int r = 0; r < 4; ++r)
      hid_p[(size_t)(pbase + t*16 + kq*4 + r)*64 + wave*16 + m15] =
        f2bf(fmaxf(p[r] + b1v, 0.f));
  }
}

// ---------------- per-node outer-product: Ghat = [sum hid⊗s | sum s | out]/c ----------------
__global__ __launch_bounds__(256) void k_outer(
    const float* __restrict__ out, const short* __restrict__ hid_p,
    const int* __restrict__ srcp, const int* __restrict__ rowstart,
    short* __restrict__ gbuf) {
  const int tid = threadIdx.x, lane = tid & 63;
  const int node = blockIdx.x * 4 + (tid >> 6);
  const int r0 = rowstart[node], r1 = rowstart[node + 1];
  const float inv = 1.f / fmaxf((float)(r1 - r0), 1.f);
  float G[64];
  #pragma unroll
  for (int r = 0; r < 64; ++r) G[r] = 0.f;
  float S = 0.f;
  int p = r0;
  for (; p + 2 <= r1; p += 2) {            // 2-edge ILP pairing
    int s0 = srcp[p], s1 = srcp[p + 1];
    float sv0 = out[(size_t)s0*64 + lane];
    float sv1 = out[(size_t)s1*64 + lane];
    float hv0 = bf2f(hid_p[(size_t)p*64 + lane]);
    float hv1 = bf2f(hid_p[(size_t)(p + 1)*64 + lane]);
    S += sv0 + sv1;
    #pragma unroll
    for (int r = 0; r < 64; ++r) {
      G[r] += __shfl(hv0, r, 64) * sv0;
      G[r] += __shfl(hv1, r, 64) * sv1;
    }
  }
  if (p < r1) {
    float sv = out[(size_t)srcp[p]*64 + lane];
    float hv = bf2f(hid_p[(size_t)p*64 + lane]);
    S += sv;
    #pragma unroll
    for (int r = 0; r < 64; ++r) G[r] += __shfl(hv, r, 64) * sv;
  }
  short* gp = gbuf + (size_t)node*KX;
  #pragma unroll
  for (int r = 0; r < 64; ++r) gp[r*64 + lane] = f2bf(G[r] * inv);
  gp[4096 + lane] = f2bf(S * inv);
  gp[4160 + lane] = f2bf(out[(size_t)node*64 + lane]);
}

// ---------------- m = Ghat @ W2ext + rootb ; softmax ; BN stats (fused) ----------------
// 256 blocks x 16 nodes; 16 waves split K=132 chunks (4x9 + 12x8); 2-batch LDS reduce.
__global__ __launch_bounds__(1024) void k_gemm2m(
    const short* __restrict__ gbuf, const short* __restrict__ w2extT,
    const float* __restrict__ rootb, const float* __restrict__ gnlin,
    float* __restrict__ m, float* __restrict__ sbuf, float* __restrict__ stats) {
  __shared__ __align__(16) float red[8*1280];   // 8 waves x 64 cols x 20 (pad)
  __shared__ float msh[16*65];
  __shared__ float lgsh[16*12];
  __shared__ float ssh[16*16];
  const int tid = threadIdx.x, lane = tid & 63, wave = tid >> 6;
  const int m15 = lane & 15, kq = lane >> 4;
  const int nb = blockIdx.x * 16;
  const f32x4 zero4 = {0.f,0.f,0.f,0.f};

  const int nch = (wave < 4) ? 9 : 8;
  const int k0  = ((wave < 4) ? wave*9 : 36 + (wave - 4)*8) * 32;

  f32x4 acc[4] = {zero4, zero4, zero4, zero4};
  const short* ga  = gbuf   + (size_t)(nb + m15)*KX + k0 + kq*8;
  const short* wb0 = w2extT + (size_t)(m15     )*KX + k0 + kq*8;
  const short* wb1 = w2extT + (size_t)(16 + m15)*KX + k0 + kq*8;
  const short* wb2 = w2extT + (size_t)(32 + m15)*KX + k0 + kq*8;
  const short* wb3 = w2extT + (size_t)(48 + m15)*KX + k0 + kq*8;
  #pragma unroll 2
  for (int c = 0; c < nch; ++c) {
    bf16x8 a  = *(const bf16x8*)(ga  + c*32);
    bf16x8 b0 = *(const bf16x8*)(wb0 + c*32);
    bf16x8 b1 = *(const bf16x8*)(wb1 + c*32);
    bf16x8 b2 = *(const bf16x8*)(wb2 + c*32);
    bf16x8 b3 = *(const bf16x8*)(wb3 + c*32);
    acc[0] = __builtin_amdgcn_mfma_f32_16x16x32_bf16(a, b0, acc[0], 0, 0, 0);
    acc[1] = __builtin_amdgcn_mfma_f32_16x16x32_bf16(a, b1, acc[1], 0, 0, 0);
    acc[2] = __builtin_amdgcn_mfma_f32_16x16x32_bf16(a, b2, acc[2], 0, 0, 0);
    acc[3] = __builtin_amdgcn_mfma_f32_16x16x32_bf16(a, b3, acc[3], 0, 0, 0);
  }

  // cross-wave reduce, two batches of 8 (LDS <= 40KB)
  // element (row = kq*4+r, col = ct*16+m15) at red[w*1280 + col*20 + row]
  if (wave < 8) {
    #pragma unroll
    for (int ct = 0; ct < 4; ++ct)
      *(f32x4*)(red + wave*1280 + (ct*16 + m15)*20 + kq*4) = acc[ct];
  }
  __syncthreads();
  const int col = tid >> 4, row = tid & 15;   // 1024 threads = 64x16 elements
  float s = 0.f;
  #pragma unroll
  for (int w = 0; w < 8; ++w) s += red[w*1280 + col*20 + row];
  __syncthreads();
  if (wave >= 8) {
    #pragma unroll
    for (int ct = 0; ct < 4; ++ct)
      *(f32x4*)(red + (wave - 8)*1280 + (ct*16 + m15)*20 + kq*4) = acc[ct];
  }
  __syncthreads();
  #pragma unroll
  for (int w = 0; w < 8; ++w) s += red[w*1280 + col*20 + row];
  msh[row*65 + col] = s + rootb[col];
  __syncthreads();

  // coalesced m write
  m[(size_t)(nb + (tid >> 6))*64 + (tid & 63)] = msh[(tid >> 6)*65 + (tid & 63)];

  // logits: 16 nodes x 10 groups
  if (tid < 160) {
    int n = tid / 10, g = tid - n*10;
    float lg = 0.f;
    #pragma unroll 8
    for (int k = 0; k < 64; ++k) lg += msh[n*65 + k] * gnlin[k*10 + g];
    lgsh[n*12 + g] = lg;
  }
  __syncthreads();
  if (tid < 256) {
    int n = tid >> 4, g = tid & 15;
    if (g < 10) {
      float mx = -1e30f;
      #pragma unroll
      for (int gg = 0; gg < 10; ++gg) mx = fmaxf(mx, lgsh[n*12 + gg]);
      float sum = 0.f;
      #pragma unroll
      for (int gg = 0; gg < 10; ++gg) sum += expf(lgsh[n*12 + gg] - mx);
      float sv = expf(lgsh[n*12 + g] - mx) / sum;
      sbuf[(nb + n)*16 + g] = sv;
      ssh[n*16 + g] = sv;
    }
  }
  __syncthreads();
  if (tid < 640) {
    int g = tid >> 6, dd = tid & 63;
    float a1 = 0.f, a2 = 0.f;
    #pragma unroll
    for (int n = 0; n < 16; ++n) {
      float t = ssh[n*16 + g] * msh[n*65 + dd];
      a1 += t; a2 += t*t;
    }
    atomicAdd(&stats[g*64 + dd], a1);
    atomicAdd(&stats[640 + g*64 + dd], a2);
  }
}

// ---------------- DGN-finalize + relu + GRU (MFMA) + residual (+ pooling on last) ----------------
__global__ __launch_bounds__(256) void k_gru(
    const float* __restrict__ m, const float* __restrict__ sbuf,
    const float* __restrict__ stats, const float* __restrict__ gamma,
    const float* __restrict__ beta, const short* __restrict__ gwihB,
    const short* __restrict__ gwhhB, const float* __restrict__ bih,
    const float* __restrict__ bhh, float* __restrict__ h,
    float* __restrict__ out, const int* __restrict__ batch,
    float* __restrict__ pooled, int do_pool) {
  __shared__ __align__(16) float mrsh[32*68];
  __shared__ float igsh[640];
  __shared__ float Bsh[64];
  __shared__ float ssh[512];
  const int tid = threadIdx.x, lane = tid & 63, wave = tid >> 6;
  const int m15 = lane & 15, kq = lane >> 4;
  const int nb = blockIdx.x * 32;
  const f32x4 zero4 = {0.f,0.f,0.f,0.f};
  const float invN = 1.f / (float)Nn;

  if (tid < 64) {
    float bacc = 0.f;
    #pragma unroll
    for (int g = 0; g < 10; ++g) {
      int c = g*64 + tid;
      float mu = stats[c] * invN;
      float var = stats[640 + c] * invN - mu*mu;
      float ig = (1.0f / sqrtf(var + EPSf)) * gamma[c];
      igsh[c] = ig;
      bacc += beta[c] - mu * ig;
    }
    Bsh[tid] = bacc;
  }
  if (tid < 512) ssh[tid] = sbuf[nb*16 + tid];
  __syncthreads();

  for (int idx = tid; idx < 2048; idx += 256) {
    int n = idx >> 6, dd = idx & 63;
    float mv = m[(nb + n)*64 + dd];
    float SA = 0.f;
    #pragma unroll
    for (int g = 0; g < 10; ++g) SA += ssh[n*16 + g] * igsh[g*64 + dd];
    mrsh[n*68 + dd] = fmaxf(mv * (1.f + LAMf*SA) + LAMf*Bsh[dd], 0.f);
  }
  __syncthreads();

  bf16x8 mrf[2][2], hf[2][2];
  #pragma unroll
  for (int t = 0; t < 2; ++t) {
    const float* mp = mrsh + (t*16 + m15)*68 + kq*8;
    const float* hp = h + (size_t)(nb + t*16 + m15)*64 + kq*8;
    #pragma unroll
    for (int ks = 0; ks < 2; ++ks) {
      mrf[t][ks] = pack8v(*(const f32x4*)(mp + ks*32), *(const f32x4*)(mp + ks*32 + 4));
      hf[t][ks]  = pack8v(*(const f32x4*)(hp + ks*32), *(const f32x4*)(hp + ks*32 + 4));
    }
  }
  const int d = wave*16 + m15;
  f32x4 gi[2][3], gh[2][3];
  #pragma unroll
  for (int p = 0; p < 3; ++p) {
    int j = p*64 + d;
    bf16x8 bi0 = *(const bf16x8*)(gwihB + j*64 + kq*8);
    bf16x8 bi1 = *(const bf16x8*)(gwihB + j*64 + 32 + kq*8);
    bf16x8 bh0 = *(const bf16x8*)(gwhhB + j*64 + kq*8);
    bf16x8 bh1 = *(const bf16x8*)(gwhhB + j*64 + 32 + kq*8);
    #pragma unroll
    for (int t = 0; t < 2; ++t) {
      f32x4 a = __builtin_amdgcn_mfma_f32_16x16x32_bf16(mrf[t][0], bi0, zero4, 0, 0, 0);
      gi[t][p] = __builtin_amdgcn_mfma_f32_16x16x32_bf16(mrf[t][1], bi1, a, 0, 0, 0);
      f32x4 b = __builtin_amdgcn_mfma_f32_16x16x32_bf16(hf[t][0], bh0, zero4, 0, 0, 0);
      gh[t][p] = __builtin_amdgcn_mfma_f32_16x16x32_bf16(hf[t][1], bh1, b, 0, 0, 0);
    }
  }
  float bir = bih[d],      bhr = bhh[d];
  float biz = bih[64 + d], bhz = bhh[64 + d];
  float bin = bih[128 + d], bhn = bhh[128 + d];
  __syncthreads();
  #pragma unroll
  for (int t = 0; t < 2; ++t) {
    #pragma unroll
    for (int r = 0; r < 4; ++r) {
      int node = nb + t*16 + kq*4 + r;
      float rr = sigm(gi[t][0][r] + bir + gh[t][0][r] + bhr);
      float z  = sigm(gi[t][1][r] + biz + gh[t][1][r] + bhz);
      float nn = tanhf(gi[t][2][r] + bin + rr * (gh[t][2][r] + bhn));
      float hv = h[node*64 + d];
      float hn = (1.f - z) * nn + z * hv;
      h[node*64 + d] = hn;
      float ov = hn + out[node*64 + d];
      out[node*64 + d] = ov;
      if (do_pool) atomicAdd(&pooled[batch[node]*64 + d], ov);
    }
  }
}

// ---------------- post FC + output ----------------
__global__ void k_final(const float* __restrict__ pooled, const float* __restrict__ pcnt,
                        const float* __restrict__ postW, const float* __restrict__ postb,
                        const float* __restrict__ outW, const float* __restrict__ outb,
                        float* __restrict__ y) {
  int b = blockIdx.x, d = threadIdx.x;
  __shared__ float pl[64];
  float c = fmaxf(pcnt[b], 1.f);
  pl[d] = pooled[b*64 + d] / c;
  __syncthreads();
  float acc = postb[d];
  #pragma unroll 8
  for (int k = 0; k < 64; ++k) acc += pl[k] * postW[k*64 + d];
  acc = fmaxf(acc, 0.f);
  float v = acc * outW[d];
  #pragma unroll
  for (int off = 32; off > 0; off >>= 1) v += __shfl_down(v, off, 64);
  if (d == 0) y[b] = v + outb[0];
}

extern "C" void kernel_launch(void* const* d_in, const int* in_sizes, int n_in,
                              void* d_out, int out_size, void* d_ws, size_t ws_size,
                              hipStream_t stream) {
  (void)in_sizes; (void)n_in; (void)out_size; (void)ws_size;
  const float* x        = (const float*)d_in[0];
  const float* edge_attr= (const float*)d_in[1];
  const float* preW     = (const float*)d_in[2];
  const float* preb     = (const float*)d_in[3];
  const float* ew1      = (const float*)d_in[4];
  const float* eb1      = (const float*)d_in[5];
  const float* ew2      = (const float*)d_in[6];
  const float* eb2      = (const float*)d_in[7];
  const float* rootw    = (const float*)d_in[8];
  const float* rootb    = (const float*)d_in[9];
  const float* gwih     = (const float*)d_in[10];
  const float* gwhh     = (const float*)d_in[11];
  const float* gbih     = (const float*)d_in[12];
  const float* gbhh     = (const float*)d_in[13];
  const float* gnlin    = (const float*)d_in[14];
  const float* gngamma  = (const float*)d_in[15];
  const float* gnbeta   = (const float*)d_in[16];
  const float* postW    = (const float*)d_in[17];
  const float* postb    = (const float*)d_in[18];
  const float* outW     = (const float*)d_in[19];
  const float* outb     = (const float*)d_in[20];
  const int*   eidx     = (const int*)d_in[21];
  const int*   batch    = (const int*)d_in[22];
  const int* src = eidx;
  const int* dst = eidx + Ee;
  float* y = (float*)d_out;

  float* ws     = (float*)d_ws;
  float* out    = ws;                     // N*64
  float* hbuf   = out    + Nn*64;         // N*64
  float* mbuf   = hbuf   + Nn*64;         // N*64
  float* sbuf   = mbuf   + Nn*64;         // N*16
  // zeroed region: cnt, stats x3, pooled, pcnt
  float* cnt    = sbuf   + Nn*16;         // N
  float* stats  = cnt    + Nn;            // 3*2048
  float* pooled = stats  + 3*2048;        // 4096
  float* pcnt   = pooled + 4096;          // 64
  int* ibase    = (int*)(pcnt + 64);
  int* rowstart = ibase;                  // 4097
  int* cursor   = rowstart + 4097;        // 4096
  int* perm     = cursor + 4096;          // E
  int* srcp     = perm + Ee;              // E
  short* sbase  = (short*)(ibase + 4097 + 4096 + Ee + Ee + 3);
  short* hid_p  = sbase;                  // E*64
  short* gbuf   = hid_p + (size_t)Ee*64;  // N*KX
  short* w2extT = gbuf + (size_t)Nn*KX;   // 3*64*KX
  short* w1T    = w2extT + 3*W2L;         // 3*4096
  short* gwihB  = w1T + 3*4096;           // 3*12288
  short* gwhhB  = gwihB + 3*12288;        // 3*12288
  short* preWT  = gwhhB + 3*12288;        // 8192

  size_t zfloats = (size_t)Nn + 3*2048 + 4096 + 64;
  hipMemsetAsync(cnt, 0, zfloats*sizeof(float), stream);

  k_setup<<<329, 256, 0, stream>>>(ew1, ew2, eb2, rootw, gwih, gwhh, preW,
                                   preb, postW, postb, outW, outb,
                                   dst, batch,
                                   w1T, w2extT, gwihB, gwhhB, preWT,
                                   cnt, pcnt, y);
  k_scan<<<1, 256, 0, stream>>>(cnt, rowstart, cursor);
  k_scatter<<<Ee/256, 256, 0, stream>>>(src, dst, cursor, perm, srcp);
  k_pre<<<Nn/32, 256, 0, stream>>>(x, preWT, preb, out, hbuf);

  for (int i = 0; i < 3; ++i) {
    k_hid<<<Ee/64, 256, 0, stream>>>(edge_attr, w1T + i*4096, eb1 + i*64, perm, hid_p);
    k_outer<<<Nn/4, 256, 0, stream>>>(out, hid_p, srcp, rowstart, gbuf);
    k_gemm2m<<<Nn/16, 1024, 0, stream>>>(gbuf, w2extT + (size_t)i*W2L,
                                         rootb + i*64, gnlin + i*640,
                                         mbuf, sbuf, stats + i*2048);
    k_gru<<<Nn/32, 256, 0, stream>>>(mbuf, sbuf, stats + i*2048,
                                     gngamma + i*640, gnbeta + i*640,
                                     gwihB + i*12288, gwhhB + i*12288,
                                     gbih + i*192, gbhh + i*192, hbuf, out,
                                     batch, pooled, (i == 2) ? 1 : 0);
  }

  k_final<<<Bb, 64, 0, stream>>>(pooled, pcnt, postW, postb, outW, outb, y);
}